// Round 2
// baseline (389.847 us; speedup 1.0000x reference)
//
#include <hip/hip_runtime.h>
#include <hip/hip_bf16.h>

#define NC 80
#define NK 51
#define REG_MAX 16
#define MAX_DET 100
#define A_TOT 8400
#define BS 16

// out layout (float32): num[16] | boxes[16*100*4] | scores[16*100] | classes[16*100] | kpts[16*100*17*3]
#define OUT_NUM 0
#define OUT_BOX 16
#define OUT_SCORE (16 + 16*MAX_DET*4)
#define OUT_CLASS (OUT_SCORE + 16*MAX_DET)
#define OUT_KPT (OUT_CLASS + 16*MAX_DET)

static __device__ __forceinline__ unsigned long long mk_key(unsigned u, int a) {
    return ((unsigned long long)u << 32) | (unsigned)(0x7FFFFFFF - a);
}

// -------- Kernel 1 v3: scalar-pipe weights, balanced grid --------
// 256 threads = 4 waves; wave wv owns ocs [wv*20, wv*20+20).
// oc0 forced into an SGPR via readfirstlane + compile-time C, so every
// weight read is an s_load with immediate offset (scalar pipe, co-issues
// with VALU; no LDS, no readlane). Each lane owns PP anchors (float2 for
// PP=2). Accumulation per (oc,anchor): bias then ascending-channel fmaf
// chain — bit-identical to v1/v2.
// Grid balance: L2 112 blocks (64-anchor, PP=1), L1 208 (128-anchor,
// PP=2), L0 800 (128-anchor, PP=2) = 1120 blocks, ~4.4/CU; per-block
// serial work ~equal (L2/L1 ~20.5K cyc, L0 ~10K cyc).
template<int C, int A, int PP>
static __device__ __forceinline__ void score_tile(
    const float* __restrict__ x, const float* __restrict__ w,
    const float* __restrict__ bias,
    int b, int a0, int a_off,
    float* __restrict__ max_s, int* __restrict__ cls_id,
    float (*rm)[128], int (*ri)[128])
{
    int t = threadIdx.x;
    int lane = t & 63;
    int wv = t >> 6;
    int oc0 = __builtin_amdgcn_readfirstlane(wv * 20);

    int aa = a0 + lane * PP;
    if (aa > A - PP) aa = A - PP;
    const float* xb = x + (long)b * C * A + aa;
    const float* wb = w + oc0 * C;            // uniform base; j*C folds to s_load imm

    float acc[20][PP];
#pragma unroll
    for (int j = 0; j < 20; ++j) {
        float bv = bias[oc0 + j];
#pragma unroll
        for (int q = 0; q < PP; ++q) acc[j][q] = bv;
    }

#pragma unroll 2
    for (int c = 0; c < C; c += 4) {
        float f[4][PP];
#pragma unroll
        for (int cc = 0; cc < 4; ++cc) {
            const float* fp = xb + (long)(c + cc) * A;
            if (PP == 2) {
                float2 v = *(const float2*)fp;
                f[cc][0] = v.x; f[cc][1] = v.y;
            } else {
                f[cc][0] = *fp;
            }
        }
#pragma unroll
        for (int j = 0; j < 20; ++j) {
            const float* wr = wb + j * C + c;
            float w0 = wr[0], w1 = wr[1], w2 = wr[2], w3 = wr[3];
#pragma unroll
            for (int q = 0; q < PP; ++q) {
                acc[j][q] = fmaf(w0, f[0][q], acc[j][q]);
                acc[j][q] = fmaf(w1, f[1][q], acc[j][q]);
                acc[j][q] = fmaf(w2, f[2][q], acc[j][q]);
                acc[j][q] = fmaf(w3, f[3][q], acc[j][q]);
            }
        }
    }

    // per-lane argmax over this wave's 20 ocs (first-max: ascending j, strict >)
#pragma unroll
    for (int q = 0; q < PP; ++q) {
        float m = acc[0][q]; int mi = 0;
#pragma unroll
        for (int j = 1; j < 20; ++j)
            if (acc[j][q] > m) { m = acc[j][q]; mi = j; }
        rm[wv][lane * PP + q] = m;
        ri[wv][lane * PP + q] = oc0 + mi;
    }
    __syncthreads();

    // cross-wave reduce: ascending wv = ascending oc keeps first-max
    if (t < 64 * PP) {
        float bm = rm[0][t]; int bi = ri[0][t];
#pragma unroll
        for (int v = 1; v < 4; ++v) {
            float om = rm[v][t];
            if (om > bm) { bm = om; bi = ri[v][t]; }
        }
        int ga = a0 + t;
        if (ga < A) {
            max_s[b * A_TOT + a_off + ga] = 1.0f / (1.0f + expf(-bm));
            cls_id[b * A_TOT + a_off + ga] = bi;
        }
    }
}

__global__ __launch_bounds__(256, 4) void scores_fused(
    const float* __restrict__ x0, const float* __restrict__ x1, const float* __restrict__ x2,
    const float* __restrict__ w0, const float* __restrict__ w1, const float* __restrict__ w2,
    const float* __restrict__ bias0, const float* __restrict__ bias1, const float* __restrict__ bias2,
    float* __restrict__ max_s,       // [BS][A_TOT]
    int* __restrict__ cls_id)        // [BS][A_TOT]
{
    __shared__ float rm[4][128];
    __shared__ int   ri[4][128];

    int bid = blockIdx.x;
    if (bid < 112) {                 // L2 first: 16 b x 7 tiles of 64 anchors
        int b = bid / 7, tile = bid - b * 7;
        score_tile<512, 400, 1>(x2, w2, bias2, b, tile * 64, 8000, max_s, cls_id, rm, ri);
    } else if (bid < 320) {          // L1: 16 b x 13 tiles of 128
        int r = bid - 112;
        int b = r / 13, tile = r - b * 13;
        score_tile<256, 1600, 2>(x1, w1, bias1, b, tile * 128, 6400, max_s, cls_id, rm, ri);
    } else {                         // L0: 16 b x 50 tiles of 128
        int r = bid - 320;
        int b = r / 50, tile = r - b * 50;
        score_tile<128, 6400, 2>(x0, w0, bias0, b, tile * 128, 0, max_s, cls_id, rm, ri);
    }
}

// -------- Kernel 2: exact top-100 per batch via radix select (unchanged) --------
__global__ __launch_bounds__(1024) void topk_kernel(
    const float* __restrict__ max_s, // [BS][A_TOT]
    const int* __restrict__ cls_id,  // [BS][A_TOT]
    float* __restrict__ out,
    int* __restrict__ top_idx)       // [BS][MAX_DET]
{
    int b = blockIdx.x;
    int t = threadIdx.x;
    int wv = t >> 6;

    __shared__ unsigned hist[16 * 256];          // per-wave histograms, 16 KB
    __shared__ unsigned suffix[256];
    __shared__ int tieIdx[A_TOT];                // 33.6 KB
    __shared__ unsigned long long highKeys[128];
    __shared__ unsigned long long finalKeys[128];
    __shared__ int wmin[16];
    __shared__ unsigned s_prefix;
    __shared__ int s_k, s_selD, s_nHigh, s_nTie, s_cnt, s_bcast;

    unsigned u[9];
    bool val[9];
#pragma unroll
    for (int i = 0; i < 9; ++i) {
        int a = t + i * 1024;
        val[i] = (a < A_TOT);
        u[i] = val[i] ? __float_as_uint(max_s[b * A_TOT + a]) : 0u;
    }

    if (t == 0) { s_prefix = 0; s_k = MAX_DET; s_nHigh = 0; s_nTie = 0; s_cnt = 0; }

    for (int pass = 0; pass < 4; ++pass) {
#pragma unroll
        for (int j = 0; j < 4; ++j) hist[t + j * 1024] = 0;
        if (t == 0) s_selD = 0;
        __syncthreads();

        unsigned pre = s_prefix;
        int k = s_k;
        int shHi = 32 - 8 * pass;
        int shD = 24 - 8 * pass;
#pragma unroll
        for (int i = 0; i < 9; ++i) {
            if (val[i]) {
                bool cand = (pass == 0) ? true : ((u[i] >> shHi) == pre);
                if (cand)
                    atomicAdd(&hist[(wv << 8) + ((u[i] >> shD) & 0xFF)], 1u);
            }
        }
        __syncthreads();

        if (t < 256) {
            unsigned s = 0;
#pragma unroll
            for (int w = 0; w < 16; ++w) s += hist[(w << 8) + t];
            suffix[t] = s;
        }
        __syncthreads();
        for (int off = 1; off < 256; off <<= 1) {
            unsigned v = 0;
            if (t < 256) v = suffix[t] + ((t + off < 256) ? suffix[t + off] : 0u);
            __syncthreads();
            if (t < 256) suffix[t] = v;
            __syncthreads();
        }
        if (t < 256 && suffix[t] >= (unsigned)k) atomicMax(&s_selD, t);
        __syncthreads();
        if (t == 0) {
            int d = s_selD;
            s_k = k - ((d < 255) ? (int)suffix[d + 1] : 0);
            s_prefix = (pre << 8) | (unsigned)d;
        }
        __syncthreads();
    }

    unsigned cut = s_prefix;
    int r = s_k;

#pragma unroll
    for (int i = 0; i < 9; ++i) {
        if (val[i]) {
            int a = t + i * 1024;
            if (u[i] > cut) {
                int p = atomicAdd(&s_nHigh, 1);
                highKeys[p] = mk_key(u[i], a);
            } else if (u[i] == cut) {
                int p = atomicAdd(&s_nTie, 1);
                tieIdx[p] = a;
            }
        }
    }
    __syncthreads();
    int m = s_nHigh;
    int nt = s_nTie;

    if (t < 128) finalKeys[t] = 0ull;
    __syncthreads();
    if (t < m) finalKeys[t] = highKeys[t];

    if (nt == r) {
        if (t < nt) finalKeys[m + t] = mk_key(cut, tieIdx[t]);
        __syncthreads();
    } else {
        __syncthreads();
        for (int j = 0; j < r; ++j) {
            int mn = 0x7FFFFFFF;
            for (int p = t; p < nt; p += 1024) mn = min(mn, tieIdx[p]);
            for (int off = 32; off > 0; off >>= 1) mn = min(mn, __shfl_down(mn, off, 64));
            if ((t & 63) == 0) wmin[wv] = mn;
            __syncthreads();
            if (t == 0) {
                int v = wmin[0];
#pragma unroll
                for (int w = 1; w < 16; ++w) v = min(v, wmin[w]);
                s_bcast = v;
                finalKeys[m + j] = mk_key(cut, v);
            }
            __syncthreads();
            int v = s_bcast;
            for (int p = t; p < nt; p += 1024)
                if (tieIdx[p] == v) tieIdx[p] = 0x7FFFFFFF;
            __syncthreads();
        }
    }

    for (int ksz = 2; ksz <= 128; ksz <<= 1) {
        for (int j = ksz >> 1; j > 0; j >>= 1) {
            if (t < 128) {
                int ixj = t ^ j;
                if (ixj > t) {
                    bool desc = ((t & ksz) == 0);
                    unsigned long long x = finalKeys[t], y = finalKeys[ixj];
                    bool sw = desc ? (x < y) : (x > y);
                    if (sw) { finalKeys[t] = y; finalKeys[ixj] = x; }
                }
            }
            __syncthreads();
        }
    }

    if (t < MAX_DET) {
        unsigned long long kk = finalKeys[t];
        float sc = __uint_as_float((unsigned)(kk >> 32));
        int a = 0x7FFFFFFF - (int)(kk & 0xFFFFFFFFull);
        out[OUT_SCORE + b * MAX_DET + t] = sc;
        out[OUT_CLASS + b * MAX_DET + t] = (float)cls_id[b * A_TOT + a];
        top_idx[b * MAX_DET + t] = a;
        if (sc > 0.25f) atomicAdd(&s_cnt, 1);
    }
    __syncthreads();
    if (t == 0) out[OUT_NUM + b] = (float)s_cnt;
}

// -------- Kernel 3: decode box + kpts for selected anchors only (unchanged) --------
__global__ __launch_bounds__(128) void decode_kernel(
    const float* __restrict__ x0, const float* __restrict__ x1, const float* __restrict__ x2,
    const float* __restrict__ w2_0, const float* __restrict__ b2_0,
    const float* __restrict__ w2_1, const float* __restrict__ b2_1,
    const float* __restrict__ w2_2, const float* __restrict__ b2_2,
    const float* __restrict__ w4_0, const float* __restrict__ b4_0,
    const float* __restrict__ w4_1, const float* __restrict__ b4_1,
    const float* __restrict__ w4_2, const float* __restrict__ b4_2,
    const int* __restrict__ top_idx,
    float* __restrict__ out)
{
    int b = blockIdx.y;
    int k = blockIdx.x;
    int a = top_idx[b * MAX_DET + k];

    const float* x; const float* w2; const float* bb2; const float* w4; const float* bb4;
    int C, A, W, a_local; float stride;
    if (a < 6400)      { x = x0; C = 128; A = 6400; W = 80; stride = 8.0f;  a_local = a;        w2 = w2_0; bb2 = b2_0; w4 = w4_0; bb4 = b4_0; }
    else if (a < 8000) { x = x1; C = 256; A = 1600; W = 40; stride = 16.0f; a_local = a - 6400; w2 = w2_1; bb2 = b2_1; w4 = w4_1; bb4 = b4_1; }
    else               { x = x2; C = 512; A = 400;  W = 20; stride = 32.0f; a_local = a - 8000; w2 = w2_2; bb2 = b2_2; w4 = w4_2; bb4 = b4_2; }

    __shared__ float fs[512];
    __shared__ float logits[64];
    __shared__ float kraw[NK];
    __shared__ float dist[4];

    int t = threadIdx.x;
    for (int c = t; c < C; c += 128)
        fs[c] = x[((long)b * C + c) * A + a_local];
    __syncthreads();

    if (t < 64 + NK) {
        const float* wrow; float acc;
        if (t < 64) { wrow = w2 + t * C; acc = bb2[t]; }
        else        { wrow = w4 + (t - 64) * C; acc = bb4[t - 64]; }
        for (int c = 0; c < C; ++c) acc = fmaf(wrow[c], fs[c], acc);
        if (t < 64) logits[t] = acc;
        else        kraw[t - 64] = acc;
    }
    __syncthreads();

    if (t < 4) {
        float mx = logits[t * 16];
#pragma unroll
        for (int r = 1; r < 16; ++r) mx = fmaxf(mx, logits[t * 16 + r]);
        float se = 0.0f, sw = 0.0f;
#pragma unroll
        for (int r = 0; r < 16; ++r) {
            float e = expf(logits[t * 16 + r] - mx);
            se += e; sw += e * (float)r;
        }
        dist[t] = sw / se;
    }
    __syncthreads();

    float ax = (float)(a_local % W) + 0.5f;
    float ay = (float)(a_local / W) + 0.5f;

    if (t == 0) {
        float x1c = ax - dist[0], y1c = ay - dist[1];
        float x2c = ax + dist[2], y2c = ay + dist[3];
        float* ob = out + OUT_BOX + ((long)b * MAX_DET + k) * 4;
        ob[0] = (x1c + x2c) * 0.5f * stride;
        ob[1] = (y1c + y2c) * 0.5f * stride;
        ob[2] = (x2c - x1c) * stride;
        ob[3] = (y2c - y1c) * stride;
    }
    if (t < 17) {
        float vx = kraw[t * 3], vy = kraw[t * 3 + 1], vv = kraw[t * 3 + 2];
        float gx = ax - 0.5f, gy = ay - 0.5f;
        float* ok = out + OUT_KPT + (((long)b * MAX_DET + k) * 17 + t) * 3;
        ok[0] = (vx * 2.0f + gx) * stride;
        ok[1] = (vy * 2.0f + gy) * stride;
        ok[2] = 1.0f / (1.0f + expf(-vv));
    }
}

extern "C" void kernel_launch(void* const* d_in, const int* in_sizes, int n_in,
                              void* d_out, int out_size, void* d_ws, size_t ws_size,
                              hipStream_t stream) {
    const float* x0 = (const float*)d_in[0];
    const float* x1 = (const float*)d_in[1];
    const float* x2 = (const float*)d_in[2];
    const float* w2[3] = {(const float*)d_in[3], (const float*)d_in[5], (const float*)d_in[7]};
    const float* b2[3] = {(const float*)d_in[4], (const float*)d_in[6], (const float*)d_in[8]};
    const float* w3[3] = {(const float*)d_in[9], (const float*)d_in[11], (const float*)d_in[13]};
    const float* b3[3] = {(const float*)d_in[10], (const float*)d_in[12], (const float*)d_in[14]};
    const float* w4[3] = {(const float*)d_in[15], (const float*)d_in[17], (const float*)d_in[19]};
    const float* b4[3] = {(const float*)d_in[16], (const float*)d_in[18], (const float*)d_in[20]};

    float* out = (float*)d_out;

    float* ws_maxs = (float*)d_ws;                    // [16][8400]
    int* ws_cls = (int*)(ws_maxs + BS * A_TOT);       // [16][8400]
    int* ws_top = (int*)(ws_cls + BS * A_TOT);        // [16][100]

    // fused scores: 112 (L2) + 208 (L1) + 800 (L0) blocks of 256 threads
    scores_fused<<<dim3(1120), 256, 0, stream>>>(
        x0, x1, x2, w3[0], w3[1], w3[2], b3[0], b3[1], b3[2], ws_maxs, ws_cls);
    topk_kernel<<<dim3(BS), 1024, 0, stream>>>(ws_maxs, ws_cls, out, ws_top);
    decode_kernel<<<dim3(MAX_DET, BS), 128, 0, stream>>>(
        x0, x1, x2,
        w2[0], b2[0], w2[1], b2[1], w2[2], b2[2],
        w4[0], b4[0], w4[1], b4[1], w4[2], b4[2],
        ws_top, out);
}

// Round 3
// 308.225 us; speedup vs baseline: 1.2648x; 1.2648x over previous
//
#include <hip/hip_runtime.h>
#include <hip/hip_bf16.h>

#define NC 80
#define NK 51
#define REG_MAX 16
#define MAX_DET 100
#define A_TOT 8400
#define BS 16

// out layout (float32): num[16] | boxes[16*100*4] | scores[16*100] | classes[16*100] | kpts[16*100*17*3]
#define OUT_NUM 0
#define OUT_BOX 16
#define OUT_SCORE (16 + 16*MAX_DET*4)
#define OUT_CLASS (OUT_SCORE + 16*MAX_DET)
#define OUT_KPT (OUT_CLASS + 16*MAX_DET)

static __device__ __forceinline__ unsigned long long mk_key(unsigned u, int a) {
    return ((unsigned long long)u << 32) | (unsigned)(0x7FFFFFFF - a);
}

// -------- Kernel 1 v4: readlane weights + work-balanced grid --------
// 512 threads = 8 waves; wave wv owns ocs [wv*10, wv*10+10).
// Weights live in a 5-VGPR rolling window (2 oc-rows x 32 ch per reg),
// broadcast per-scalar via v_readlane (VALU, no LDS pipe, no s_load in
// the loop — v3's scalar-pipe stall and v1's LDS-broadcast bound both
// avoided). Features: direct coalesced global loads (float4/2/1), no
// barriers in the K-loop.
// Work balance (v2's killer was the 4-unit L2 tail): every block does
// C*anchors = 32768: L2 64-anchor PP=1, L1 128-anchor PP=2, L0
// 256-anchor PP=4. 720 blocks -> 5.6 waves/SIMD, work-limited wall.
// Accumulation per (oc,anchor): bias then ascending-channel fmaf chain —
// bit-identical to v1/v2/v3.
template<int C, int A, int PP>
static __device__ __forceinline__ void score_tile(
    const float* __restrict__ x, const float* __restrict__ w,
    const float* __restrict__ bias,
    int b, int a0, int a_off,
    float* __restrict__ max_s, int* __restrict__ cls_id,
    float (*rm)[256], int (*ri)[256])
{
    int t = threadIdx.x;
    int lane = t & 63;
    int wv = t >> 6;
    int oc0 = wv * 10;

    int aa = a0 + lane * PP;
    if (aa > A - PP) aa = A - PP;
    const float* xb = x + (long)b * C * A + aa;

    // weight VGPR window: reg r2 holds ocs (oc0+2*r2, oc0+2*r2+1);
    // lanes 0-31 = row oc0+2*r2, lanes 32-63 = row oc0+2*r2+1; col = lane&31
    int wrow = oc0 + (lane >> 5);
    int wcol = lane & 31;

    float acc[10][PP];
#pragma unroll
    for (int j = 0; j < 10; ++j) {
        float bv = bias[oc0 + j];
#pragma unroll
        for (int q = 0; q < PP; ++q) acc[j][q] = bv;
    }

    int nchunk = C >> 5;
    float wcur[5], wnxt[5];
#pragma unroll
    for (int r2 = 0; r2 < 5; ++r2)
        wcur[r2] = w[(wrow + 2 * r2) * C + wcol];

    for (int kc = 0; kc < nchunk; ++kc) {
        int cbase = kc * 32;
        // prefetch next chunk's weights (5 coalesced loads, no LDS/scalar)
        if (kc + 1 < nchunk) {
#pragma unroll
            for (int r2 = 0; r2 < 5; ++r2)
                wnxt[r2] = w[(wrow + 2 * r2) * C + cbase + 32 + wcol];
        }

#pragma unroll 2
        for (int c4 = 0; c4 < 32; c4 += 4) {
            float f[4][PP];
#pragma unroll
            for (int cc = 0; cc < 4; ++cc) {
                const float* fp = xb + (long)(cbase + c4 + cc) * A;
                if constexpr (PP == 4) {
                    float4 v = *(const float4*)fp;
                    f[cc][0] = v.x; f[cc][1] = v.y; f[cc][2] = v.z; f[cc][3] = v.w;
                } else if constexpr (PP == 2) {
                    float2 v = *(const float2*)fp;
                    f[cc][0] = v.x; f[cc][1] = v.y;
                } else {
                    f[cc][0] = *fp;
                }
            }
#pragma unroll
            for (int j = 0; j < 10; ++j) {
                int rr = j >> 1;
                int hi = (j & 1) << 5;
                float ws0 = __int_as_float(__builtin_amdgcn_readlane(__float_as_int(wcur[rr]), hi + c4 + 0));
                float ws1 = __int_as_float(__builtin_amdgcn_readlane(__float_as_int(wcur[rr]), hi + c4 + 1));
                float ws2 = __int_as_float(__builtin_amdgcn_readlane(__float_as_int(wcur[rr]), hi + c4 + 2));
                float ws3 = __int_as_float(__builtin_amdgcn_readlane(__float_as_int(wcur[rr]), hi + c4 + 3));
#pragma unroll
                for (int q = 0; q < PP; ++q) {
                    // ascending-channel chain per anchor (bit-identical)
                    acc[j][q] = fmaf(ws0, f[0][q], acc[j][q]);
                    acc[j][q] = fmaf(ws1, f[1][q], acc[j][q]);
                    acc[j][q] = fmaf(ws2, f[2][q], acc[j][q]);
                    acc[j][q] = fmaf(ws3, f[3][q], acc[j][q]);
                }
            }
        }

        if (kc + 1 < nchunk) {
#pragma unroll
            for (int r2 = 0; r2 < 5; ++r2) wcur[r2] = wnxt[r2];
        }
    }

    // per-lane argmax over this wave's 10 ocs (first-max: ascending j, strict >)
#pragma unroll
    for (int q = 0; q < PP; ++q) {
        float m = acc[0][q]; int mi = 0;
#pragma unroll
        for (int j = 1; j < 10; ++j)
            if (acc[j][q] > m) { m = acc[j][q]; mi = j; }
        rm[wv][lane * PP + q] = m;
        ri[wv][lane * PP + q] = oc0 + mi;
    }
    __syncthreads();

    // cross-wave reduce: ascending wv = ascending oc keeps first-max
    if (t < 64 * PP) {
        float bm = rm[0][t]; int bi = ri[0][t];
#pragma unroll
        for (int v = 1; v < 8; ++v) {
            float om = rm[v][t];
            if (om > bm) { bm = om; bi = ri[v][t]; }
        }
        int ga = a0 + t;
        if (ga < A) {
            max_s[b * A_TOT + a_off + ga] = 1.0f / (1.0f + expf(-bm));
            cls_id[b * A_TOT + a_off + ga] = bi;
        }
    }
}

__global__ __launch_bounds__(512, 4) void scores_fused(
    const float* __restrict__ x0, const float* __restrict__ x1, const float* __restrict__ x2,
    const float* __restrict__ w0, const float* __restrict__ w1, const float* __restrict__ w2,
    const float* __restrict__ bias0, const float* __restrict__ bias1, const float* __restrict__ bias2,
    float* __restrict__ max_s,       // [BS][A_TOT]
    int* __restrict__ cls_id)        // [BS][A_TOT]
{
    __shared__ float rm[8][256];
    __shared__ int   ri[8][256];

    int bid = blockIdx.x;
    if (bid < 112) {                 // L2: 16 b x 7 tiles of 64 anchors, PP=1
        int b = bid / 7, tile = bid - b * 7;
        score_tile<512, 400, 1>(x2, w2, bias2, b, tile * 64, 8000, max_s, cls_id, rm, ri);
    } else if (bid < 320) {          // L1: 16 b x 13 tiles of 128, PP=2
        int r = bid - 112;
        int b = r / 13, tile = r - b * 13;
        score_tile<256, 1600, 2>(x1, w1, bias1, b, tile * 128, 6400, max_s, cls_id, rm, ri);
    } else {                         // L0: 16 b x 25 tiles of 256, PP=4
        int r = bid - 320;
        int b = r / 25, tile = r - b * 25;
        score_tile<128, 6400, 4>(x0, w0, bias0, b, tile * 256, 0, max_s, cls_id, rm, ri);
    }
}

// -------- Kernel 2: exact top-100 per batch via radix select (unchanged) --------
__global__ __launch_bounds__(1024) void topk_kernel(
    const float* __restrict__ max_s, // [BS][A_TOT]
    const int* __restrict__ cls_id,  // [BS][A_TOT]
    float* __restrict__ out,
    int* __restrict__ top_idx)       // [BS][MAX_DET]
{
    int b = blockIdx.x;
    int t = threadIdx.x;
    int wv = t >> 6;

    __shared__ unsigned hist[16 * 256];          // per-wave histograms, 16 KB
    __shared__ unsigned suffix[256];
    __shared__ int tieIdx[A_TOT];                // 33.6 KB
    __shared__ unsigned long long highKeys[128];
    __shared__ unsigned long long finalKeys[128];
    __shared__ int wmin[16];
    __shared__ unsigned s_prefix;
    __shared__ int s_k, s_selD, s_nHigh, s_nTie, s_cnt, s_bcast;

    unsigned u[9];
    bool val[9];
#pragma unroll
    for (int i = 0; i < 9; ++i) {
        int a = t + i * 1024;
        val[i] = (a < A_TOT);
        u[i] = val[i] ? __float_as_uint(max_s[b * A_TOT + a]) : 0u;
    }

    if (t == 0) { s_prefix = 0; s_k = MAX_DET; s_nHigh = 0; s_nTie = 0; s_cnt = 0; }

    for (int pass = 0; pass < 4; ++pass) {
#pragma unroll
        for (int j = 0; j < 4; ++j) hist[t + j * 1024] = 0;
        if (t == 0) s_selD = 0;
        __syncthreads();

        unsigned pre = s_prefix;
        int k = s_k;
        int shHi = 32 - 8 * pass;
        int shD = 24 - 8 * pass;
#pragma unroll
        for (int i = 0; i < 9; ++i) {
            if (val[i]) {
                bool cand = (pass == 0) ? true : ((u[i] >> shHi) == pre);
                if (cand)
                    atomicAdd(&hist[(wv << 8) + ((u[i] >> shD) & 0xFF)], 1u);
            }
        }
        __syncthreads();

        if (t < 256) {
            unsigned s = 0;
#pragma unroll
            for (int w = 0; w < 16; ++w) s += hist[(w << 8) + t];
            suffix[t] = s;
        }
        __syncthreads();
        for (int off = 1; off < 256; off <<= 1) {
            unsigned v = 0;
            if (t < 256) v = suffix[t] + ((t + off < 256) ? suffix[t + off] : 0u);
            __syncthreads();
            if (t < 256) suffix[t] = v;
            __syncthreads();
        }
        if (t < 256 && suffix[t] >= (unsigned)k) atomicMax(&s_selD, t);
        __syncthreads();
        if (t == 0) {
            int d = s_selD;
            s_k = k - ((d < 255) ? (int)suffix[d + 1] : 0);
            s_prefix = (pre << 8) | (unsigned)d;
        }
        __syncthreads();
    }

    unsigned cut = s_prefix;
    int r = s_k;

#pragma unroll
    for (int i = 0; i < 9; ++i) {
        if (val[i]) {
            int a = t + i * 1024;
            if (u[i] > cut) {
                int p = atomicAdd(&s_nHigh, 1);
                highKeys[p] = mk_key(u[i], a);
            } else if (u[i] == cut) {
                int p = atomicAdd(&s_nTie, 1);
                tieIdx[p] = a;
            }
        }
    }
    __syncthreads();
    int m = s_nHigh;
    int nt = s_nTie;

    if (t < 128) finalKeys[t] = 0ull;
    __syncthreads();
    if (t < m) finalKeys[t] = highKeys[t];

    if (nt == r) {
        if (t < nt) finalKeys[m + t] = mk_key(cut, tieIdx[t]);
        __syncthreads();
    } else {
        __syncthreads();
        for (int j = 0; j < r; ++j) {
            int mn = 0x7FFFFFFF;
            for (int p = t; p < nt; p += 1024) mn = min(mn, tieIdx[p]);
            for (int off = 32; off > 0; off >>= 1) mn = min(mn, __shfl_down(mn, off, 64));
            if ((t & 63) == 0) wmin[wv] = mn;
            __syncthreads();
            if (t == 0) {
                int v = wmin[0];
#pragma unroll
                for (int w = 1; w < 16; ++w) v = min(v, wmin[w]);
                s_bcast = v;
                finalKeys[m + j] = mk_key(cut, v);
            }
            __syncthreads();
            int v = s_bcast;
            for (int p = t; p < nt; p += 1024)
                if (tieIdx[p] == v) tieIdx[p] = 0x7FFFFFFF;
            __syncthreads();
        }
    }

    for (int ksz = 2; ksz <= 128; ksz <<= 1) {
        for (int j = ksz >> 1; j > 0; j >>= 1) {
            if (t < 128) {
                int ixj = t ^ j;
                if (ixj > t) {
                    bool desc = ((t & ksz) == 0);
                    unsigned long long x = finalKeys[t], y = finalKeys[ixj];
                    bool sw = desc ? (x < y) : (x > y);
                    if (sw) { finalKeys[t] = y; finalKeys[ixj] = x; }
                }
            }
            __syncthreads();
        }
    }

    if (t < MAX_DET) {
        unsigned long long kk = finalKeys[t];
        float sc = __uint_as_float((unsigned)(kk >> 32));
        int a = 0x7FFFFFFF - (int)(kk & 0xFFFFFFFFull);
        out[OUT_SCORE + b * MAX_DET + t] = sc;
        out[OUT_CLASS + b * MAX_DET + t] = (float)cls_id[b * A_TOT + a];
        top_idx[b * MAX_DET + t] = a;
        if (sc > 0.25f) atomicAdd(&s_cnt, 1);
    }
    __syncthreads();
    if (t == 0) out[OUT_NUM + b] = (float)s_cnt;
}

// -------- Kernel 3: decode box + kpts for selected anchors only (unchanged) --------
__global__ __launch_bounds__(128) void decode_kernel(
    const float* __restrict__ x0, const float* __restrict__ x1, const float* __restrict__ x2,
    const float* __restrict__ w2_0, const float* __restrict__ b2_0,
    const float* __restrict__ w2_1, const float* __restrict__ b2_1,
    const float* __restrict__ w2_2, const float* __restrict__ b2_2,
    const float* __restrict__ w4_0, const float* __restrict__ b4_0,
    const float* __restrict__ w4_1, const float* __restrict__ b4_1,
    const float* __restrict__ w4_2, const float* __restrict__ b4_2,
    const int* __restrict__ top_idx,
    float* __restrict__ out)
{
    int b = blockIdx.y;
    int k = blockIdx.x;
    int a = top_idx[b * MAX_DET + k];

    const float* x; const float* w2; const float* bb2; const float* w4; const float* bb4;
    int C, A, W, a_local; float stride;
    if (a < 6400)      { x = x0; C = 128; A = 6400; W = 80; stride = 8.0f;  a_local = a;        w2 = w2_0; bb2 = b2_0; w4 = w4_0; bb4 = b4_0; }
    else if (a < 8000) { x = x1; C = 256; A = 1600; W = 40; stride = 16.0f; a_local = a - 6400; w2 = w2_1; bb2 = b2_1; w4 = w4_1; bb4 = b4_1; }
    else               { x = x2; C = 512; A = 400;  W = 20; stride = 32.0f; a_local = a - 8000; w2 = w2_2; bb2 = b2_2; w4 = w4_2; bb4 = b4_2; }

    __shared__ float fs[512];
    __shared__ float logits[64];
    __shared__ float kraw[NK];
    __shared__ float dist[4];

    int t = threadIdx.x;
    for (int c = t; c < C; c += 128)
        fs[c] = x[((long)b * C + c) * A + a_local];
    __syncthreads();

    if (t < 64 + NK) {
        const float* wrow; float acc;
        if (t < 64) { wrow = w2 + t * C; acc = bb2[t]; }
        else        { wrow = w4 + (t - 64) * C; acc = bb4[t - 64]; }
        for (int c = 0; c < C; ++c) acc = fmaf(wrow[c], fs[c], acc);
        if (t < 64) logits[t] = acc;
        else        kraw[t - 64] = acc;
    }
    __syncthreads();

    if (t < 4) {
        float mx = logits[t * 16];
#pragma unroll
        for (int r = 1; r < 16; ++r) mx = fmaxf(mx, logits[t * 16 + r]);
        float se = 0.0f, sw = 0.0f;
#pragma unroll
        for (int r = 0; r < 16; ++r) {
            float e = expf(logits[t * 16 + r] - mx);
            se += e; sw += e * (float)r;
        }
        dist[t] = sw / se;
    }
    __syncthreads();

    float ax = (float)(a_local % W) + 0.5f;
    float ay = (float)(a_local / W) + 0.5f;

    if (t == 0) {
        float x1c = ax - dist[0], y1c = ay - dist[1];
        float x2c = ax + dist[2], y2c = ay + dist[3];
        float* ob = out + OUT_BOX + ((long)b * MAX_DET + k) * 4;
        ob[0] = (x1c + x2c) * 0.5f * stride;
        ob[1] = (y1c + y2c) * 0.5f * stride;
        ob[2] = (x2c - x1c) * stride;
        ob[3] = (y2c - y1c) * stride;
    }
    if (t < 17) {
        float vx = kraw[t * 3], vy = kraw[t * 3 + 1], vv = kraw[t * 3 + 2];
        float gx = ax - 0.5f, gy = ay - 0.5f;
        float* ok = out + OUT_KPT + (((long)b * MAX_DET + k) * 17 + t) * 3;
        ok[0] = (vx * 2.0f + gx) * stride;
        ok[1] = (vy * 2.0f + gy) * stride;
        ok[2] = 1.0f / (1.0f + expf(-vv));
    }
}

extern "C" void kernel_launch(void* const* d_in, const int* in_sizes, int n_in,
                              void* d_out, int out_size, void* d_ws, size_t ws_size,
                              hipStream_t stream) {
    const float* x0 = (const float*)d_in[0];
    const float* x1 = (const float*)d_in[1];
    const float* x2 = (const float*)d_in[2];
    const float* w2[3] = {(const float*)d_in[3], (const float*)d_in[5], (const float*)d_in[7]};
    const float* b2[3] = {(const float*)d_in[4], (const float*)d_in[6], (const float*)d_in[8]};
    const float* w3[3] = {(const float*)d_in[9], (const float*)d_in[11], (const float*)d_in[13]};
    const float* b3[3] = {(const float*)d_in[10], (const float*)d_in[12], (const float*)d_in[14]};
    const float* w4[3] = {(const float*)d_in[15], (const float*)d_in[17], (const float*)d_in[19]};
    const float* b4[3] = {(const float*)d_in[16], (const float*)d_in[18], (const float*)d_in[20]};

    float* out = (float*)d_out;

    float* ws_maxs = (float*)d_ws;                    // [16][8400]
    int* ws_cls = (int*)(ws_maxs + BS * A_TOT);       // [16][8400]
    int* ws_top = (int*)(ws_cls + BS * A_TOT);        // [16][100]

    // fused scores: 112 (L2) + 208 (L1) + 400 (L0) blocks of 512 threads
    scores_fused<<<dim3(720), 512, 0, stream>>>(
        x0, x1, x2, w3[0], w3[1], w3[2], b3[0], b3[1], b3[2], ws_maxs, ws_cls);
    topk_kernel<<<dim3(BS), 1024, 0, stream>>>(ws_maxs, ws_cls, out, ws_top);
    decode_kernel<<<dim3(MAX_DET, BS), 128, 0, stream>>>(
        x0, x1, x2,
        w2[0], b2[0], w2[1], b2[1], w2[2], b2[2],
        w4[0], b4[0], w4[1], b4[1], w4[2], b4[2],
        ws_top, out);
}

// Round 4
// 305.802 us; speedup vs baseline: 1.2748x; 1.0079x over previous
//
#include <hip/hip_runtime.h>
#include <hip/hip_bf16.h>

#define NC 80
#define NK 51
#define REG_MAX 16
#define MAX_DET 100
#define A_TOT 8400
#define BS 16

// out layout (float32): num[16] | boxes[16*100*4] | scores[16*100] | classes[16*100] | kpts[16*100*17*3]
#define OUT_NUM 0
#define OUT_BOX 16
#define OUT_SCORE (16 + 16*MAX_DET*4)
#define OUT_CLASS (OUT_SCORE + 16*MAX_DET)
#define OUT_KPT (OUT_CLASS + 16*MAX_DET)

static __device__ __forceinline__ unsigned long long mk_key(unsigned u, int a) {
    return ((unsigned long long)u << 32) | (unsigned)(0x7FFFFFFF - a);
}

// -------- Kernel 1 v5: LDS-broadcast weights at tileA=256 --------
// Readlane measured ~8 cy (v4: 66% VALUBusy = 70 us busy for 38 us of
// model work -> readlane-issue-bound). ds_read_b128 uniform broadcast
// measured ~8.5 cy (v1 calibration). Per c4 group the CU needs exactly
// 80 broadcast b128s (~680 LDS-cy) REGARDLESS of oc/wave split, while
// VALU demand = 2.5*tileA cy -> LDS-broadcast is VALU-bound iff
// tileA >= ~272. So: uniform 256-anchor tiles, PP=4, at ALL levels.
// 512 threads = 8 waves; wave wv owns ocs [wv*10, wv*10+10).
// Weights: staged per 32-ch chunk into LDS (10 KB), read as wave-uniform
// float4 (broadcast, conflict-free). Features: direct coalesced global
// float4 (4 consecutive anchors per lane). Accumulation per (oc,anchor):
// bias then ascending-channel fmaf chain - bit-identical to v1-v4.
template<int C, int A>
static __device__ __forceinline__ void score_tile(
    const float* __restrict__ x, const float* __restrict__ w,
    const float* __restrict__ bias,
    int b, int a0, int a_off,
    float* __restrict__ max_s, int* __restrict__ cls_id,
    float* __restrict__ wsh, float (*rm)[256], int (*ri)[256])
{
    int t = threadIdx.x;
    int lane = t & 63;
    int wv = t >> 6;
    int oc0 = wv * 10;

    int aa = a0 + lane * 4;
    if (aa > A - 4) aa = A - 4;            // ragged tiles: duplicate last anchors, writes guarded
    const float* xb = x + (long)b * C * A + aa;

    float acc[10][4];
#pragma unroll
    for (int j = 0; j < 10; ++j) {
        float bv = bias[oc0 + j];
        acc[j][0] = bv; acc[j][1] = bv; acc[j][2] = bv; acc[j][3] = bv;
    }

    int nchunk = C >> 5;
    for (int kc = 0; kc < nchunk; ++kc) {
        int cbase = kc * 32;
        if (kc) __syncthreads();           // prev compute done before restage
        // stage 80 ocs x 32 ch = 640 float4
#pragma unroll
        for (int i = 0; i < 2; ++i) {
            int idx = t + i * 512;
            if (idx < 640) {
                int oc = idx >> 3;
                int q = idx & 7;
                float4 v = *(const float4*)(w + oc * C + cbase + q * 4);
                *(float4*)(&wsh[idx * 4]) = v;
            }
        }
        __syncthreads();

#pragma unroll 2
        for (int c4 = 0; c4 < 32; c4 += 4) {
            const float* fp = xb + (long)(cbase + c4) * A;
            float4 f0 = *(const float4*)(fp);
            float4 f1 = *(const float4*)(fp + A);
            float4 f2 = *(const float4*)(fp + 2 * A);
            float4 f3 = *(const float4*)(fp + 3 * A);
#pragma unroll
            for (int j = 0; j < 10; ++j) {
                float4 w4 = *(const float4*)(&wsh[(oc0 + j) * 32 + c4]);  // uniform broadcast
                // ascending-channel chain per anchor (bit-identical)
                acc[j][0] = fmaf(w4.x, f0.x, acc[j][0]);
                acc[j][0] = fmaf(w4.y, f1.x, acc[j][0]);
                acc[j][0] = fmaf(w4.z, f2.x, acc[j][0]);
                acc[j][0] = fmaf(w4.w, f3.x, acc[j][0]);
                acc[j][1] = fmaf(w4.x, f0.y, acc[j][1]);
                acc[j][1] = fmaf(w4.y, f1.y, acc[j][1]);
                acc[j][1] = fmaf(w4.z, f2.y, acc[j][1]);
                acc[j][1] = fmaf(w4.w, f3.y, acc[j][1]);
                acc[j][2] = fmaf(w4.x, f0.z, acc[j][2]);
                acc[j][2] = fmaf(w4.y, f1.z, acc[j][2]);
                acc[j][2] = fmaf(w4.z, f2.z, acc[j][2]);
                acc[j][2] = fmaf(w4.w, f3.z, acc[j][2]);
                acc[j][3] = fmaf(w4.x, f0.w, acc[j][3]);
                acc[j][3] = fmaf(w4.y, f1.w, acc[j][3]);
                acc[j][3] = fmaf(w4.z, f2.w, acc[j][3]);
                acc[j][3] = fmaf(w4.w, f3.w, acc[j][3]);
            }
        }
    }

    // per-lane argmax over this wave's 10 ocs (first-max: ascending j, strict >)
#pragma unroll
    for (int q = 0; q < 4; ++q) {
        float m = acc[0][q]; int mi = 0;
#pragma unroll
        for (int j = 1; j < 10; ++j)
            if (acc[j][q] > m) { m = acc[j][q]; mi = j; }
        rm[wv][lane * 4 + q] = m;
        ri[wv][lane * 4 + q] = oc0 + mi;
    }
    __syncthreads();

    // cross-wave reduce: ascending wv = ascending oc keeps first-max
    if (t < 256) {
        float bm = rm[0][t]; int bi = ri[0][t];
#pragma unroll
        for (int v = 1; v < 8; ++v) {
            float om = rm[v][t];
            if (om > bm) { bm = om; bi = ri[v][t]; }
        }
        int ga = a0 + t;
        if (ga < A) {
            max_s[b * A_TOT + a_off + ga] = 1.0f / (1.0f + expf(-bm));
            cls_id[b * A_TOT + a_off + ga] = bi;
        }
    }
}

__global__ __launch_bounds__(512, 3) void scores_fused(
    const float* __restrict__ x0, const float* __restrict__ x1, const float* __restrict__ x2,
    const float* __restrict__ w0, const float* __restrict__ w1, const float* __restrict__ w2,
    const float* __restrict__ bias0, const float* __restrict__ bias1, const float* __restrict__ bias2,
    float* __restrict__ max_s,       // [BS][A_TOT]
    int* __restrict__ cls_id)        // [BS][A_TOT]
{
    __shared__ float wsh[80 * 32];   // 10 KB weight chunk
    __shared__ float rm[8][256];
    __shared__ int   ri[8][256];

    int bid = blockIdx.x;
    if (bid < 32) {                  // L2 first: 16 b x 2 tiles of 256 (heavy, solo CUs)
        int b = bid >> 1, tile = bid & 1;
        score_tile<512, 400>(x2, w2, bias2, b, tile * 256, 8000, max_s, cls_id, wsh, rm, ri);
    } else if (bid < 144) {          // L1: 16 b x 7 tiles of 256 (ragged, clamped)
        int r = bid - 32;
        int b = r / 7, tile = r - b * 7;
        score_tile<256, 1600>(x1, w1, bias1, b, tile * 256, 6400, max_s, cls_id, wsh, rm, ri);
    } else {                         // L0: 16 b x 25 tiles of 256
        int r = bid - 144;
        int b = r / 25, tile = r - b * 25;
        score_tile<128, 6400>(x0, w0, bias0, b, tile * 256, 0, max_s, cls_id, wsh, rm, ri);
    }
}

// -------- Kernel 2: exact top-100 per batch via radix select (unchanged) --------
__global__ __launch_bounds__(1024) void topk_kernel(
    const float* __restrict__ max_s, // [BS][A_TOT]
    const int* __restrict__ cls_id,  // [BS][A_TOT]
    float* __restrict__ out,
    int* __restrict__ top_idx)       // [BS][MAX_DET]
{
    int b = blockIdx.x;
    int t = threadIdx.x;
    int wv = t >> 6;

    __shared__ unsigned hist[16 * 256];          // per-wave histograms, 16 KB
    __shared__ unsigned suffix[256];
    __shared__ int tieIdx[A_TOT];                // 33.6 KB
    __shared__ unsigned long long highKeys[128];
    __shared__ unsigned long long finalKeys[128];
    __shared__ int wmin[16];
    __shared__ unsigned s_prefix;
    __shared__ int s_k, s_selD, s_nHigh, s_nTie, s_cnt, s_bcast;

    unsigned u[9];
    bool val[9];
#pragma unroll
    for (int i = 0; i < 9; ++i) {
        int a = t + i * 1024;
        val[i] = (a < A_TOT);
        u[i] = val[i] ? __float_as_uint(max_s[b * A_TOT + a]) : 0u;
    }

    if (t == 0) { s_prefix = 0; s_k = MAX_DET; s_nHigh = 0; s_nTie = 0; s_cnt = 0; }

    for (int pass = 0; pass < 4; ++pass) {
#pragma unroll
        for (int j = 0; j < 4; ++j) hist[t + j * 1024] = 0;
        if (t == 0) s_selD = 0;
        __syncthreads();

        unsigned pre = s_prefix;
        int k = s_k;
        int shHi = 32 - 8 * pass;
        int shD = 24 - 8 * pass;
#pragma unroll
        for (int i = 0; i < 9; ++i) {
            if (val[i]) {
                bool cand = (pass == 0) ? true : ((u[i] >> shHi) == pre);
                if (cand)
                    atomicAdd(&hist[(wv << 8) + ((u[i] >> shD) & 0xFF)], 1u);
            }
        }
        __syncthreads();

        if (t < 256) {
            unsigned s = 0;
#pragma unroll
            for (int w = 0; w < 16; ++w) s += hist[(w << 8) + t];
            suffix[t] = s;
        }
        __syncthreads();
        for (int off = 1; off < 256; off <<= 1) {
            unsigned v = 0;
            if (t < 256) v = suffix[t] + ((t + off < 256) ? suffix[t + off] : 0u);
            __syncthreads();
            if (t < 256) suffix[t] = v;
            __syncthreads();
        }
        if (t < 256 && suffix[t] >= (unsigned)k) atomicMax(&s_selD, t);
        __syncthreads();
        if (t == 0) {
            int d = s_selD;
            s_k = k - ((d < 255) ? (int)suffix[d + 1] : 0);
            s_prefix = (pre << 8) | (unsigned)d;
        }
        __syncthreads();
    }

    unsigned cut = s_prefix;
    int r = s_k;

#pragma unroll
    for (int i = 0; i < 9; ++i) {
        if (val[i]) {
            int a = t + i * 1024;
            if (u[i] > cut) {
                int p = atomicAdd(&s_nHigh, 1);
                highKeys[p] = mk_key(u[i], a);
            } else if (u[i] == cut) {
                int p = atomicAdd(&s_nTie, 1);
                tieIdx[p] = a;
            }
        }
    }
    __syncthreads();
    int m = s_nHigh;
    int nt = s_nTie;

    if (t < 128) finalKeys[t] = 0ull;
    __syncthreads();
    if (t < m) finalKeys[t] = highKeys[t];

    if (nt == r) {
        if (t < nt) finalKeys[m + t] = mk_key(cut, tieIdx[t]);
        __syncthreads();
    } else {
        __syncthreads();
        for (int j = 0; j < r; ++j) {
            int mn = 0x7FFFFFFF;
            for (int p = t; p < nt; p += 1024) mn = min(mn, tieIdx[p]);
            for (int off = 32; off > 0; off >>= 1) mn = min(mn, __shfl_down(mn, off, 64));
            if ((t & 63) == 0) wmin[wv] = mn;
            __syncthreads();
            if (t == 0) {
                int v = wmin[0];
#pragma unroll
                for (int w = 1; w < 16; ++w) v = min(v, wmin[w]);
                s_bcast = v;
                finalKeys[m + j] = mk_key(cut, v);
            }
            __syncthreads();
            int v = s_bcast;
            for (int p = t; p < nt; p += 1024)
                if (tieIdx[p] == v) tieIdx[p] = 0x7FFFFFFF;
            __syncthreads();
        }
    }

    for (int ksz = 2; ksz <= 128; ksz <<= 1) {
        for (int j = ksz >> 1; j > 0; j >>= 1) {
            if (t < 128) {
                int ixj = t ^ j;
                if (ixj > t) {
                    bool desc = ((t & ksz) == 0);
                    unsigned long long x = finalKeys[t], y = finalKeys[ixj];
                    bool sw = desc ? (x < y) : (x > y);
                    if (sw) { finalKeys[t] = y; finalKeys[ixj] = x; }
                }
            }
            __syncthreads();
        }
    }

    if (t < MAX_DET) {
        unsigned long long kk = finalKeys[t];
        float sc = __uint_as_float((unsigned)(kk >> 32));
        int a = 0x7FFFFFFF - (int)(kk & 0xFFFFFFFFull);
        out[OUT_SCORE + b * MAX_DET + t] = sc;
        out[OUT_CLASS + b * MAX_DET + t] = (float)cls_id[b * A_TOT + a];
        top_idx[b * MAX_DET + t] = a;
        if (sc > 0.25f) atomicAdd(&s_cnt, 1);
    }
    __syncthreads();
    if (t == 0) out[OUT_NUM + b] = (float)s_cnt;
}

// -------- Kernel 3: decode box + kpts for selected anchors only (unchanged) --------
__global__ __launch_bounds__(128) void decode_kernel(
    const float* __restrict__ x0, const float* __restrict__ x1, const float* __restrict__ x2,
    const float* __restrict__ w2_0, const float* __restrict__ b2_0,
    const float* __restrict__ w2_1, const float* __restrict__ b2_1,
    const float* __restrict__ w2_2, const float* __restrict__ b2_2,
    const float* __restrict__ w4_0, const float* __restrict__ b4_0,
    const float* __restrict__ w4_1, const float* __restrict__ b4_1,
    const float* __restrict__ w4_2, const float* __restrict__ b4_2,
    const int* __restrict__ top_idx,
    float* __restrict__ out)
{
    int b = blockIdx.y;
    int k = blockIdx.x;
    int a = top_idx[b * MAX_DET + k];

    const float* x; const float* w2; const float* bb2; const float* w4; const float* bb4;
    int C, A, W, a_local; float stride;
    if (a < 6400)      { x = x0; C = 128; A = 6400; W = 80; stride = 8.0f;  a_local = a;        w2 = w2_0; bb2 = b2_0; w4 = w4_0; bb4 = b4_0; }
    else if (a < 8000) { x = x1; C = 256; A = 1600; W = 40; stride = 16.0f; a_local = a - 6400; w2 = w2_1; bb2 = b2_1; w4 = w4_1; bb4 = b4_1; }
    else               { x = x2; C = 512; A = 400;  W = 20; stride = 32.0f; a_local = a - 8000; w2 = w2_2; bb2 = b2_2; w4 = w4_2; bb4 = b4_2; }

    __shared__ float fs[512];
    __shared__ float logits[64];
    __shared__ float kraw[NK];
    __shared__ float dist[4];

    int t = threadIdx.x;
    for (int c = t; c < C; c += 128)
        fs[c] = x[((long)b * C + c) * A + a_local];
    __syncthreads();

    if (t < 64 + NK) {
        const float* wrow; float acc;
        if (t < 64) { wrow = w2 + t * C; acc = bb2[t]; }
        else        { wrow = w4 + (t - 64) * C; acc = bb4[t - 64]; }
        for (int c = 0; c < C; ++c) acc = fmaf(wrow[c], fs[c], acc);
        if (t < 64) logits[t] = acc;
        else        kraw[t - 64] = acc;
    }
    __syncthreads();

    if (t < 4) {
        float mx = logits[t * 16];
#pragma unroll
        for (int r = 1; r < 16; ++r) mx = fmaxf(mx, logits[t * 16 + r]);
        float se = 0.0f, sw = 0.0f;
#pragma unroll
        for (int r = 0; r < 16; ++r) {
            float e = expf(logits[t * 16 + r] - mx);
            se += e; sw += e * (float)r;
        }
        dist[t] = sw / se;
    }
    __syncthreads();

    float ax = (float)(a_local % W) + 0.5f;
    float ay = (float)(a_local / W) + 0.5f;

    if (t == 0) {
        float x1c = ax - dist[0], y1c = ay - dist[1];
        float x2c = ax + dist[2], y2c = ay + dist[3];
        float* ob = out + OUT_BOX + ((long)b * MAX_DET + k) * 4;
        ob[0] = (x1c + x2c) * 0.5f * stride;
        ob[1] = (y1c + y2c) * 0.5f * stride;
        ob[2] = (x2c - x1c) * stride;
        ob[3] = (y2c - y1c) * stride;
    }
    if (t < 17) {
        float vx = kraw[t * 3], vy = kraw[t * 3 + 1], vv = kraw[t * 3 + 2];
        float gx = ax - 0.5f, gy = ay - 0.5f;
        float* ok = out + OUT_KPT + (((long)b * MAX_DET + k) * 17 + t) * 3;
        ok[0] = (vx * 2.0f + gx) * stride;
        ok[1] = (vy * 2.0f + gy) * stride;
        ok[2] = 1.0f / (1.0f + expf(-vv));
    }
}

extern "C" void kernel_launch(void* const* d_in, const int* in_sizes, int n_in,
                              void* d_out, int out_size, void* d_ws, size_t ws_size,
                              hipStream_t stream) {
    const float* x0 = (const float*)d_in[0];
    const float* x1 = (const float*)d_in[1];
    const float* x2 = (const float*)d_in[2];
    const float* w2[3] = {(const float*)d_in[3], (const float*)d_in[5], (const float*)d_in[7]};
    const float* b2[3] = {(const float*)d_in[4], (const float*)d_in[6], (const float*)d_in[8]};
    const float* w3[3] = {(const float*)d_in[9], (const float*)d_in[11], (const float*)d_in[13]};
    const float* b3[3] = {(const float*)d_in[10], (const float*)d_in[12], (const float*)d_in[14]};
    const float* w4[3] = {(const float*)d_in[15], (const float*)d_in[17], (const float*)d_in[19]};
    const float* b4[3] = {(const float*)d_in[16], (const float*)d_in[18], (const float*)d_in[20]};

    float* out = (float*)d_out;

    float* ws_maxs = (float*)d_ws;                    // [16][8400]
    int* ws_cls = (int*)(ws_maxs + BS * A_TOT);       // [16][8400]
    int* ws_top = (int*)(ws_cls + BS * A_TOT);        // [16][100]

    // fused scores: 32 (L2) + 112 (L1) + 400 (L0) blocks of 512 threads
    scores_fused<<<dim3(544), 512, 0, stream>>>(
        x0, x1, x2, w3[0], w3[1], w3[2], b3[0], b3[1], b3[2], ws_maxs, ws_cls);
    topk_kernel<<<dim3(BS), 1024, 0, stream>>>(ws_maxs, ws_cls, out, ws_top);
    decode_kernel<<<dim3(MAX_DET, BS), 128, 0, stream>>>(
        x0, x1, x2,
        w2[0], b2[0], w2[1], b2[1], w2[2], b2[2],
        w4[0], b4[0], w4[1], b4[1], w4[2], b4[2],
        ws_top, out);
}